// Round 8
// baseline (307.369 us; speedup 1.0000x reference)
//
#include <hip/hip_runtime.h>
#include <math.h>

#define N_NODES 50000
#define N_EDGES 800000
#define LAGS 16
#define FILT 64
#define QSIZE 12500          // node-quarter size (LDS histogram: 50 KB)
#define NSLICE 16            // edge slices of 50000 edges each
// weight tensor (2, 2, 80, 64): w[d][k][c][f] flat = ((d*2+k)*80 + c)*64 + f
// Only rows c<16 matter (H0 == 0). w_r/b_r entirely dead (R*H0 == 0).
// H = (1-Z)*H_tilde since Z*H0 == 0.
#define W00_OFF 0            // d=0,k=0 identity hop
#define W01_OFF (80*64)      // d=0,k=1 out-diffusion hop
#define W10_OFF (2*80*64)    // d=1,k=0 identity hop
#define W11_OFF (3*80*64)    // d=1,k=1 in-diffusion hop

// HW fp32 fadd atomic (global): lowers to global_atomic_add_f32, no CAS loop.
// NOTE (r6 profile): each global fp atomic is a 32B memory-side transaction
// (cross-XCD coherence bypasses L2); random-address scalar atomics run at
// ~19 G tx/s (deg_kernel: 1.6M atomics = 83.4 us, WRITE_SIZE 49.8 MB).
// Use ONLY where line-packed (scatter) — never random-scalar.
__device__ __forceinline__ void atomAddF(float* p, float v) {
    unsafeAtomicAdd(p, v);
}

// ---------------- kernel 1: degree partial-histograms (NO global atomics) --
// Grid 128 blocks: b = [dir:1][quarter:2][slice:4].
// Block scans slice s (50000 edges), LDS-accumulates weights of nodes in its
// 12500-node quarter (native ds_add_f32), then flushes its quarter to
// part[(dir*NSLICE+s)*N_NODES + quarter] with coalesced non-atomic stores.
// Replaces r6's deg_kernel: 83.4 us of random 32B atomic tx -> ~10 us of
// L2-resident reads + 12.8 MB coalesced writes.
__global__ __launch_bounds__(256) void hist_kernel(
    const int* __restrict__ row, const int* __restrict__ col,
    const float* __restrict__ ew,
    float* __restrict__ part)
{
    __shared__ float hist[QSIZE];
    const int b   = blockIdx.x;
    const int dir = b >> 6;           // 0: out-degree (row), 1: in-degree (col)
    const int q   = (b >> 4) & 3;     // node quarter
    const int s   = b & 15;           // edge slice
    const int* __restrict__ idx = dir ? col : row;

    for (int i = threadIdx.x; i < QSIZE; i += 256) hist[i] = 0.0f;
    __syncthreads();

    const int ebase = s * (N_EDGES / NSLICE);
    const int qbase = q * QSIZE;
    for (int e = ebase + threadIdx.x; e < ebase + N_EDGES / NSLICE; e += 256) {
        int n = idx[e];
        float w = ew[e];
        unsigned u = (unsigned)(n - qbase);
        if (u < QSIZE) atomicAdd(&hist[u], w);   // ds_add_f32
    }
    __syncthreads();

    float* dst = part + (size_t)(dir * NSLICE + s) * N_NODES + qbase;
    for (int i = threadIdx.x; i < QSIZE; i += 256) dst[i] = hist[i];
}

// ---------------- kernel 2: reduce partials + guarded recip + pre-scale ----
// deg_out[n] = sum_s part[s][n]; deg_in[n] = sum_s part[NSLICE+s][n]
// Xs_o[n] = x[n] * (deg_out>0 ? 1/deg_out : 1); Xs_i likewise.
// Fuses r6's scale_kernel. All loads coalesced (stride-N_NODES partials).
__global__ __launch_bounds__(256) void reduce_scale_kernel(
    const float* __restrict__ part, const float* __restrict__ x,
    float* __restrict__ Xs_o, float* __restrict__ Xs_i)
{
    int n = blockIdx.x * 256 + threadIdx.x;
    if (n >= N_NODES) return;
    float so = 0.0f, si = 0.0f;
#pragma unroll
    for (int s = 0; s < NSLICE; ++s) {
        so += part[(size_t)s * N_NODES + n];
        si += part[(size_t)(NSLICE + s) * N_NODES + n];
    }
    float io = (so > 0.0f) ? (1.0f / so) : 1.0f;
    float ii = (si > 0.0f) ? (1.0f / si) : 1.0f;
    const float4* px = (const float4*)(x + (size_t)n * LAGS);
    float4* po = (float4*)(Xs_o + (size_t)n * LAGS);
    float4* pi = (float4*)(Xs_i + (size_t)n * LAGS);
#pragma unroll
    for (int qq = 0; qq < 4; ++qq) {
        float4 v = px[qq];
        po[qq] = make_float4(io * v.x, io * v.y, io * v.z, io * v.w);
        pi[qq] = make_float4(ii * v.x, ii * v.y, ii * v.z, ii * v.w);
    }
}

// ---------------- kernel 3: edge scatter, lane-per-channel ----------------
// 16 lanes own one edge (lane ch = tid&15 handles channel ch):
//   Tx_o[col][ch] += Xs_o[row][ch];  Tx_i[row][ch] += Xs_i[col][ch]
// Line-packed: 16 lane-atomics merge into ~1 line transaction (r6 evidence:
// 25.6M lane-atomics ran FASTER than deg's 1.6M random-scalar atomics).
__global__ __launch_bounds__(256) void scatter_kernel(
    const int* __restrict__ row, const int* __restrict__ col,
    const float* __restrict__ Xs_o, const float* __restrict__ Xs_i,
    float* __restrict__ Tx_o, float* __restrict__ Tx_i)
{
    const int total = N_EDGES * 16;   // 12.8M lane-tasks
    for (int t = blockIdx.x * 256 + threadIdx.x; t < total;
         t += gridDim.x * 256) {
        int e  = t >> 4;
        int ch = t & 15;
        int r = row[e], c = col[e];
        float vo = Xs_o[(size_t)r * LAGS + ch];
        float vi = Xs_i[(size_t)c * LAGS + ch];
        atomAddF(&Tx_o[(size_t)c * LAGS + ch], vo);
        atomAddF(&Tx_i[(size_t)r * LAGS + ch], vi);
    }
}

// ---------------- kernel 4: fused per-node gates + head ----------------
// gz = x@(Wz00+Wz10)[:16] + Tx_o@Wz01[:16] + Tx_i@Wz11[:16] + bz
// gh = same with w_h
// out = relu((1-sigmoid(gz))*tanh(gh)) @ lin_w + lin_b
__global__ __launch_bounds__(256) void node_kernel(
    const float* __restrict__ x,
    const float* __restrict__ Tx_o, const float* __restrict__ Tx_i,
    const float* __restrict__ w_z, const float* __restrict__ b_z,
    const float* __restrict__ w_h, const float* __restrict__ b_h,
    const float* __restrict__ lin_w, const float* __restrict__ lin_b,
    float* __restrict__ out)
{
    __shared__ float Wzc[FILT * 16], Wzo[FILT * 16], Wzi[FILT * 16];
    __shared__ float Whc[FILT * 16], Who[FILT * 16], Whi[FILT * 16];
    __shared__ float sbz[FILT], sbh[FILT], slw[FILT];

    const int tid = threadIdx.x;
    for (int i = tid; i < FILT * 16; i += 256) {
        int c = i >> 6, f = i & 63;           // global reads coalesced over f
        int t = f * 16 + c;
        int g = c * 64 + f;
        Wzc[t] = w_z[W00_OFF + g] + w_z[W10_OFF + g];
        Wzo[t] = w_z[W01_OFF + g];
        Wzi[t] = w_z[W11_OFF + g];
        Whc[t] = w_h[W00_OFF + g] + w_h[W10_OFF + g];
        Who[t] = w_h[W01_OFF + g];
        Whi[t] = w_h[W11_OFF + g];
    }
    if (tid < FILT) {
        sbz[tid] = b_z[tid];
        sbh[tid] = b_h[tid];
        slw[tid] = lin_w[tid];
    }
    __syncthreads();

    int n = blockIdx.x * 256 + tid;
    if (n >= N_NODES) return;

    float v[48];   // x | Tx_o | Tx_i, 16 each
    {
        float4* vv = (float4*)v;
        const float4* px = (const float4*)(x    + (size_t)n * LAGS);
        const float4* po = (const float4*)(Tx_o + (size_t)n * LAGS);
        const float4* pi = (const float4*)(Tx_i + (size_t)n * LAGS);
#pragma unroll
        for (int q = 0; q < 4; ++q) {
            vv[q] = px[q]; vv[4 + q] = po[q]; vv[8 + q] = pi[q];
        }
    }

    float acc = 0.0f;
    for (int f = 0; f < FILT; ++f) {
        float az = sbz[f], ah = sbh[f];
        const float4* wzc = (const float4*)&Wzc[f * 16];
        const float4* wzo = (const float4*)&Wzo[f * 16];
        const float4* wzi = (const float4*)&Wzi[f * 16];
        const float4* whc = (const float4*)&Whc[f * 16];
        const float4* who = (const float4*)&Who[f * 16];
        const float4* whi = (const float4*)&Whi[f * 16];
#pragma unroll
        for (int q = 0; q < 4; ++q) {
            float4 a = wzc[q], b = wzo[q], cc = wzi[q];
            float4 d = whc[q], e = who[q], g = whi[q];
            const float* vx = &v[q * 4];
            const float* vo = &v[16 + q * 4];
            const float* vi = &v[32 + q * 4];
            az = fmaf(vx[0], a.x, az);  ah = fmaf(vx[0], d.x, ah);
            az = fmaf(vx[1], a.y, az);  ah = fmaf(vx[1], d.y, ah);
            az = fmaf(vx[2], a.z, az);  ah = fmaf(vx[2], d.z, ah);
            az = fmaf(vx[3], a.w, az);  ah = fmaf(vx[3], d.w, ah);
            az = fmaf(vo[0], b.x, az);  ah = fmaf(vo[0], e.x, ah);
            az = fmaf(vo[1], b.y, az);  ah = fmaf(vo[1], e.y, ah);
            az = fmaf(vo[2], b.z, az);  ah = fmaf(vo[2], e.z, ah);
            az = fmaf(vo[3], b.w, az);  ah = fmaf(vo[3], e.w, ah);
            az = fmaf(vi[0], cc.x, az); ah = fmaf(vi[0], g.x, ah);
            az = fmaf(vi[1], cc.y, az); ah = fmaf(vi[1], g.y, ah);
            az = fmaf(vi[2], cc.z, az); ah = fmaf(vi[2], g.z, ah);
            az = fmaf(vi[3], cc.w, az); ah = fmaf(vi[3], g.w, ah);
        }
        float z = 1.0f / (1.0f + __expf(-az));                 // sigmoid
        float th = 1.0f - 2.0f / (__expf(2.0f * ah) + 1.0f);   // tanh
        acc = fmaf(fmaxf((1.0f - z) * th, 0.0f), slw[f], acc);
    }
    out[n] = acc + lin_b[0];
}

extern "C" void kernel_launch(void* const* d_in, const int* in_sizes, int n_in,
                              void* d_out, int out_size, void* d_ws, size_t ws_size,
                              hipStream_t stream)
{
    const float* x      = (const float*)d_in[0];
    const int*   eidx   = (const int*)d_in[1];      // (2, E) int32 per harness
    const float* ew     = (const float*)d_in[2];
    const float* w_z    = (const float*)d_in[3];
    const float* b_z    = (const float*)d_in[4];
    // d_in[5], d_in[6] = w_r, b_r : dead (H0 == 0 => R*H0 == 0)
    const float* w_h    = (const float*)d_in[7];
    const float* b_h    = (const float*)d_in[8];
    const float* lin_w  = (const float*)d_in[9];
    const float* lin_b  = (const float*)d_in[10];
    float* out = (float*)d_out;

    const int* row = eidx;            // edge_index[0]
    const int* col = eidx + N_EDGES;  // edge_index[1]

    // workspace (floats), 64N total = 12.8 MB:
    //   [0, 32N)   : part[2*NSLICE][N] during deg phase, ALIASED to
    //                Tx_o[16N] | Tx_i[16N] afterwards (part dead after
    //                reduce; stream-ordered memset re-zeros the region).
    //   [32N, 64N) : Xs_o[16N] | Xs_i[16N]
    float* ws   = (float*)d_ws;
    float* part = ws;
    float* Tx_o = ws;                        // alias of part[0 .. 16N)
    float* Tx_i = ws + 16 * N_NODES;         // alias of part[16N .. 32N)
    float* Xs_o = ws + 32 * N_NODES;
    float* Xs_i = ws + 48 * N_NODES;

    // 1) degree partial histograms (no global atomics; part fully written)
    hist_kernel<<<128, 256, 0, stream>>>(row, col, ew, part);

    // 2) reduce partials -> guarded reciprocal -> pre-scaled features
    int nb = (N_NODES + 255) / 256;
    reduce_scale_kernel<<<nb, 256, 0, stream>>>(part, x, Xs_o, Xs_i);

    // 3) zero Tx (reuses part region; ordered after reduce on the stream)
    hipMemsetAsync(ws, 0, (size_t)32 * N_NODES * sizeof(float), stream);

    // 4) edge scatter (line-packed atomics)
    scatter_kernel<<<2048, 256, 0, stream>>>(row, col, Xs_o, Xs_i, Tx_o, Tx_i);

    // 5) fused gates + head
    node_kernel<<<nb, 256, 0, stream>>>(x, Tx_o, Tx_i, w_z, b_z, w_h, b_h,
                                        lin_w, lin_b, out);
}

// Round 12
// 264.638 us; speedup vs baseline: 1.1615x; 1.1615x over previous
//
#include <hip/hip_runtime.h>
#include <math.h>

#define N_NODES 50000
#define N_EDGES 800000
#define LAGS 16
#define FILT 64
#define QSIZE 6250           // node-eighth (LDS histogram: 25 KB)
#define NQ 8                 // node eighths
#define NSLICE 32            // edge slices of 25000 edges
#define ESLICE (N_EDGES / NSLICE)
// weight tensor (2, 2, 80, 64): w[d][k][c][f] flat = ((d*2+k)*80 + c)*64 + f
// Only rows c<16 matter (H0 == 0). w_r/b_r entirely dead (R*H0 == 0).
// H = (1-Z)*H_tilde since Z*H0 == 0.
#define W00_OFF 0            // d=0,k=0 identity hop
#define W01_OFF (80*64)      // d=0,k=1 out-diffusion hop
#define W10_OFF (2*80*64)    // d=1,k=0 identity hop
#define W11_OFF (3*80*64)    // d=1,k=1 in-diffusion hop

// HW fp32 fadd atomic, no CAS loop (works for global AND LDS pointers).
// ATOMIC LAW (r6 measured): memory-side fp atomics are 32B-granule tx at
// ~19-20 G tx/s chip-wide (deg_kernel: 1.6M random-scalar = 83 us,
// WRITE_SIZE 49.8 MB = 32 B/tx). Line-packed lanes merge; random scalars
// don't. Keep hot-path atomic TX count minimal.
__device__ __forceinline__ void atomAddF(float* p, float v) {
    unsafeAtomicAdd(p, v);
}

// ---------------- kernel 1: degree LDS-histograms, line-packed flush -------
// r8 post-mortem: 128 blocks / 1 wave-per-SIMD was latency-serialized
// (124-158 us, occupancy 5%, VALU 1%). Now 512 blocks (2 dirs x 8 eighths x
// 32 slices), 25 KB LDS each -> 2 blocks/CU, 8 waves/CU, unroll-4 ILP.
// LDS adds use unsafeAtomicAdd (guaranteed ds_add_f32, no CAS-loop risk).
// Flush adds the block's eighth straight into deg[] with line-packed global
// atomics (consecutive lanes -> consecutive floats): ~200K line-tx total.
__global__ __launch_bounds__(256) void hist_kernel(
    const int* __restrict__ row, const int* __restrict__ col,
    const float* __restrict__ ew,
    float* __restrict__ deg_out, float* __restrict__ deg_in)
{
    __shared__ float hist[QSIZE];
    const int b   = blockIdx.x;
    const int dir = b >> 8;           // 0: out-degree (row), 1: in-degree (col)
    const int q   = (b >> 5) & 7;     // node eighth
    const int s   = b & 31;           // edge slice
    const int* __restrict__ idx = dir ? col : row;

    for (int i = threadIdx.x; i < QSIZE; i += 256) hist[i] = 0.0f;
    __syncthreads();

    const int ebase = s * ESLICE;
    const int qbase = q * QSIZE;
#pragma unroll 4
    for (int e = ebase + threadIdx.x; e < ebase + ESLICE; e += 256) {
        int n = idx[e];
        float w = ew[e];
        unsigned u = (unsigned)(n - qbase);
        if (u < QSIZE) atomAddF(&hist[u], w);    // ds_add_f32
    }
    __syncthreads();

    float* dst = (dir ? deg_in : deg_out) + qbase;
    for (int i = threadIdx.x; i < QSIZE; i += 256)
        atomAddF(&dst[i], hist[i]);              // line-packed flush
}

// ---------------- kernel 2: recip + pre-scale + Tx zero --------------------
// Xs_o[n] = x[n] * (deg_out[n] > 0 ? 1/deg_out[n] : 1)
// Xs_i[n] = x[n] * (deg_in[n]  > 0 ? 1/deg_in[n]  : 1)
// Also zeroes Tx_o[n], Tx_i[n] rows (same coalesced pass; replaces a
// 12.8 MB stream-serialized memset).
__global__ __launch_bounds__(256) void scale_kernel(
    const float* __restrict__ x,
    const float* __restrict__ deg_out, const float* __restrict__ deg_in,
    float* __restrict__ Xs_o, float* __restrict__ Xs_i,
    float* __restrict__ Tx_o, float* __restrict__ Tx_i)
{
    int n = blockIdx.x * 256 + threadIdx.x;
    if (n >= N_NODES) return;
    float d_o = deg_out[n];
    float d_i = deg_in[n];
    float io = (d_o > 0.0f) ? (1.0f / d_o) : 1.0f;
    float ii = (d_i > 0.0f) ? (1.0f / d_i) : 1.0f;
    const float4* px = (const float4*)(x + (size_t)n * LAGS);
    float4* po = (float4*)(Xs_o + (size_t)n * LAGS);
    float4* pi = (float4*)(Xs_i + (size_t)n * LAGS);
    float4* zo = (float4*)(Tx_o + (size_t)n * LAGS);
    float4* zi = (float4*)(Tx_i + (size_t)n * LAGS);
    const float4 zero = make_float4(0.f, 0.f, 0.f, 0.f);
#pragma unroll
    for (int q = 0; q < 4; ++q) {
        float4 v = px[q];
        po[q] = make_float4(io * v.x, io * v.y, io * v.z, io * v.w);
        pi[q] = make_float4(ii * v.x, ii * v.y, ii * v.z, ii * v.w);
        zo[q] = zero;
        zi[q] = zero;
    }
}

// ---------------- kernel 3: edge scatter, lane-per-channel ----------------
// 16 lanes own one edge (lane ch = tid&15 handles channel ch):
//   Tx_o[col][ch] += Xs_o[row][ch];  Tx_i[row][ch] += Xs_i[col][ch]
// Line-packed: 16 consecutive lane-atomics per 64B row. Predicted ~1.6M tx
// (or 3.2M if the 32B granule splits each row) -> 80-160 us, THE number to
// read from this profile.
__global__ __launch_bounds__(256) void scatter_kernel(
    const int* __restrict__ row, const int* __restrict__ col,
    const float* __restrict__ Xs_o, const float* __restrict__ Xs_i,
    float* __restrict__ Tx_o, float* __restrict__ Tx_i)
{
    const int total = N_EDGES * 16;   // 12.8M lane-tasks
    for (int t = blockIdx.x * 256 + threadIdx.x; t < total;
         t += gridDim.x * 256) {
        int e  = t >> 4;
        int ch = t & 15;
        int r = row[e], c = col[e];
        float vo = Xs_o[(size_t)r * LAGS + ch];
        float vi = Xs_i[(size_t)c * LAGS + ch];
        atomAddF(&Tx_o[(size_t)c * LAGS + ch], vo);
        atomAddF(&Tx_i[(size_t)r * LAGS + ch], vi);
    }
}

// ---------------- kernel 4: fused per-node gates + head ----------------
// gz = x@(Wz00+Wz10)[:16] + Tx_o@Wz01[:16] + Tx_i@Wz11[:16] + bz
// gh = same with w_h
// out = relu((1-sigmoid(gz))*tanh(gh)) @ lin_w + lin_b
__global__ __launch_bounds__(256) void node_kernel(
    const float* __restrict__ x,
    const float* __restrict__ Tx_o, const float* __restrict__ Tx_i,
    const float* __restrict__ w_z, const float* __restrict__ b_z,
    const float* __restrict__ w_h, const float* __restrict__ b_h,
    const float* __restrict__ lin_w, const float* __restrict__ lin_b,
    float* __restrict__ out)
{
    __shared__ float Wzc[FILT * 16], Wzo[FILT * 16], Wzi[FILT * 16];
    __shared__ float Whc[FILT * 16], Who[FILT * 16], Whi[FILT * 16];
    __shared__ float sbz[FILT], sbh[FILT], slw[FILT];

    const int tid = threadIdx.x;
    for (int i = tid; i < FILT * 16; i += 256) {
        int c = i >> 6, f = i & 63;           // global reads coalesced over f
        int t = f * 16 + c;
        int g = c * 64 + f;
        Wzc[t] = w_z[W00_OFF + g] + w_z[W10_OFF + g];
        Wzo[t] = w_z[W01_OFF + g];
        Wzi[t] = w_z[W11_OFF + g];
        Whc[t] = w_h[W00_OFF + g] + w_h[W10_OFF + g];
        Who[t] = w_h[W01_OFF + g];
        Whi[t] = w_h[W11_OFF + g];
    }
    if (tid < FILT) {
        sbz[tid] = b_z[tid];
        sbh[tid] = b_h[tid];
        slw[tid] = lin_w[tid];
    }
    __syncthreads();

    int n = blockIdx.x * 256 + tid;
    if (n >= N_NODES) return;

    float v[48];   // x | Tx_o | Tx_i, 16 each
    {
        float4* vv = (float4*)v;
        const float4* px = (const float4*)(x    + (size_t)n * LAGS);
        const float4* po = (const float4*)(Tx_o + (size_t)n * LAGS);
        const float4* pi = (const float4*)(Tx_i + (size_t)n * LAGS);
#pragma unroll
        for (int q = 0; q < 4; ++q) {
            vv[q] = px[q]; vv[4 + q] = po[q]; vv[8 + q] = pi[q];
        }
    }

    float acc = 0.0f;
    for (int f = 0; f < FILT; ++f) {
        float az = sbz[f], ah = sbh[f];
        const float4* wzc = (const float4*)&Wzc[f * 16];
        const float4* wzo = (const float4*)&Wzo[f * 16];
        const float4* wzi = (const float4*)&Wzi[f * 16];
        const float4* whc = (const float4*)&Whc[f * 16];
        const float4* who = (const float4*)&Who[f * 16];
        const float4* whi = (const float4*)&Whi[f * 16];
#pragma unroll
        for (int q = 0; q < 4; ++q) {
            float4 a = wzc[q], b = wzo[q], cc = wzi[q];
            float4 d = whc[q], e = who[q], g = whi[q];
            const float* vx = &v[q * 4];
            const float* vo = &v[16 + q * 4];
            const float* vi = &v[32 + q * 4];
            az = fmaf(vx[0], a.x, az);  ah = fmaf(vx[0], d.x, ah);
            az = fmaf(vx[1], a.y, az);  ah = fmaf(vx[1], d.y, ah);
            az = fmaf(vx[2], a.z, az);  ah = fmaf(vx[2], d.z, ah);
            az = fmaf(vx[3], a.w, az);  ah = fmaf(vx[3], d.w, ah);
            az = fmaf(vo[0], b.x, az);  ah = fmaf(vo[0], e.x, ah);
            az = fmaf(vo[1], b.y, az);  ah = fmaf(vo[1], e.y, ah);
            az = fmaf(vo[2], b.z, az);  ah = fmaf(vo[2], e.z, ah);
            az = fmaf(vo[3], b.w, az);  ah = fmaf(vo[3], e.w, ah);
            az = fmaf(vi[0], cc.x, az); ah = fmaf(vi[0], g.x, ah);
            az = fmaf(vi[1], cc.y, az); ah = fmaf(vi[1], g.y, ah);
            az = fmaf(vi[2], cc.z, az); ah = fmaf(vi[2], g.z, ah);
            az = fmaf(vi[3], cc.w, az); ah = fmaf(vi[3], g.w, ah);
        }
        float z = 1.0f / (1.0f + __expf(-az));                 // sigmoid
        float th = 1.0f - 2.0f / (__expf(2.0f * ah) + 1.0f);   // tanh
        acc = fmaf(fmaxf((1.0f - z) * th, 0.0f), slw[f], acc);
    }
    out[n] = acc + lin_b[0];
}

extern "C" void kernel_launch(void* const* d_in, const int* in_sizes, int n_in,
                              void* d_out, int out_size, void* d_ws, size_t ws_size,
                              hipStream_t stream)
{
    const float* x      = (const float*)d_in[0];
    const int*   eidx   = (const int*)d_in[1];      // (2, E) int32 per harness
    const float* ew     = (const float*)d_in[2];
    const float* w_z    = (const float*)d_in[3];
    const float* b_z    = (const float*)d_in[4];
    // d_in[5], d_in[6] = w_r, b_r : dead (H0 == 0 => R*H0 == 0)
    const float* w_h    = (const float*)d_in[7];
    const float* b_h    = (const float*)d_in[8];
    const float* lin_w  = (const float*)d_in[9];
    const float* lin_b  = (const float*)d_in[10];
    float* out = (float*)d_out;

    const int* row = eidx;            // edge_index[0]
    const int* col = eidx + N_EDGES;  // edge_index[1]

    // workspace (floats), 66N total = 13.2 MB:
    //   deg_out N | deg_in N | Tx_o 16N | Tx_i 16N | Xs_o 16N | Xs_i 16N
    // Only deg (2N) memset; Tx zeroed inside scale_kernel.
    float* ws      = (float*)d_ws;
    float* deg_out = ws;
    float* deg_in  = ws + N_NODES;
    float* Tx_o    = ws + 2 * N_NODES;
    float* Tx_i    = ws + 2 * N_NODES + 16 * N_NODES;
    float* Xs_o    = ws + 2 * N_NODES + 32 * N_NODES;
    float* Xs_i    = ws + 2 * N_NODES + 48 * N_NODES;

    hipMemsetAsync(ws, 0, (size_t)2 * N_NODES * sizeof(float), stream);

    // 1) degree histograms (512 blocks; LDS accumulate, line-packed flush)
    hist_kernel<<<2 * NQ * NSLICE, 256, 0, stream>>>(row, col, ew,
                                                     deg_out, deg_in);

    // 2) guarded reciprocal -> pre-scaled features; zero Tx
    int nb = (N_NODES + 255) / 256;
    scale_kernel<<<nb, 256, 0, stream>>>(x, deg_out, deg_in,
                                         Xs_o, Xs_i, Tx_o, Tx_i);

    // 3) edge scatter (line-packed atomics)
    scatter_kernel<<<2048, 256, 0, stream>>>(row, col, Xs_o, Xs_i, Tx_o, Tx_i);

    // 4) fused gates + head
    node_kernel<<<nb, 256, 0, stream>>>(x, Tx_o, Tx_i, w_z, b_z, w_h, b_h,
                                        lin_w, lin_b, out);
}